// Round 9
// baseline (2209.891 us; speedup 1.0000x reference)
//
#include <hip/hip_runtime.h>

// ---------------------------------------------------------------------------
// 2-layer tanh RNN, B=64, T=512, I=256, H=512.  Round 14: R13 champion
// skeleton + sentinel dataflow (notify == data, one LLC transaction).
//   - h slabs 1..T pre-filled 0xFFFFFFFF (fp16 NaN|NaN); fast_tanh output is
//     never NaN, so "dword != -1" == arrived.  Producers: R13's coalesced 8B
//     sc1 stores, but NO drain, NO flag, NO publish barrier.  Consumers:
//     each thread sc1-polls ITS OWN 16B stage unit until clean, then writes
//     it to LDS -- the poll result IS the staged data.
//   - L0: ONE barrier/step (stage LDS double-buffered; per-wave order proof:
//     MFMA-reads of buf[p] complete before S(t), stage-writes of buf[p]
//     happen after S(t+1) -- disjoint by barrier).  L1: S + R barriers
//     (R protects stage & red reuse), part pairs as in R13.
//   - everything else byte-identical to R13: staging geometry, MFMA mapping,
//     LDS swizzle, fp16 weights, fast_tanh, xw precompute into d_out,
//     epilogue transpose, slab rotation, finalize.
// ---------------------------------------------------------------------------

#define kB 64
#define kT 512
#define kI 256
#define kH 512
#define kBH (kB * kH)   // 32768

typedef _Float16 half8 __attribute__((ext_vector_type(8)));
typedef float floatx4 __attribute__((ext_vector_type(4)));
typedef unsigned u32x4 __attribute__((ext_vector_type(4)));
typedef unsigned u32x2 __attribute__((ext_vector_type(2)));

#define MFMA(a, b, c) __builtin_amdgcn_mfma_f32_16x16x32_f16(a, b, c, 0, 0, 0)

// ws layout (bytes)
constexpr size_t W16_B   = 0;                      // wih0 fp16, 256 KB
constexpr size_t WH0_B   = 1u * 1024 * 1024;       // whh0 fp16, 512 KB
constexpr size_t WI1_B   = WH0_B + 512u * 1024;    // wih1 fp16, 512 KB
constexpr size_t WH1_B   = WI1_B + 512u * 1024;    // whh1 fp16, 512 KB
constexpr size_t OUT0M_B = 16u * 1024 * 1024;                     // [T+1][B][H] fp16
constexpr size_t H1M_B   = OUT0M_B + (size_t)(kT + 1) * kBH * 2;  // [T+1][B][H] fp16

__device__ inline void agent_store8(void* p, u32x2 v) {
    asm volatile("global_store_dwordx2 %0, %1, off sc1" :: "v"(p), "v"(v) : "memory");
}
#define LLC_LOAD16(dst, p) \
    asm volatile("global_load_dwordx4 %0, %1, off sc1" : "=v"(dst) : "v"(p))

__device__ inline unsigned dirty4(u32x4 v) {
    unsigned m01 = v[0] > v[1] ? v[0] : v[1];
    unsigned m23 = v[2] > v[3] ? v[2] : v[3];
    unsigned m = m01 > m23 ? m01 : m23;
    return m == 0xFFFFFFFFu;   // any dword still the sentinel
}

__device__ inline float fast_tanh(float x) {
    float e = __expf(2.f * x);
    return 1.f - 2.f / (e + 1.f);   // exact +-1 saturation, no NaN
}

__device__ inline half8 cvt8(const float* p) {
    const float4* p4 = (const float4*)p;
    float4 a = p4[0], b = p4[1];
    half8 h;
    h[0] = (_Float16)a.x; h[1] = (_Float16)a.y; h[2] = (_Float16)a.z; h[3] = (_Float16)a.w;
    h[4] = (_Float16)b.x; h[5] = (_Float16)b.y; h[6] = (_Float16)b.z; h[7] = (_Float16)b.w;
    return h;
}

// ---------------------------------------------------------------------------
__global__ void setup_kernel(const float* __restrict__ h0,
                             const float* __restrict__ wih0, const float* __restrict__ whh0,
                             const float* __restrict__ wih1, const float* __restrict__ whh1,
                             _Float16* __restrict__ w16, _Float16* __restrict__ wh0_16,
                             _Float16* __restrict__ wi1_16, _Float16* __restrict__ wh1_16,
                             _Float16* __restrict__ out0m, _Float16* __restrict__ h1m) {
    size_t tid = (size_t)blockIdx.x * blockDim.x + threadIdx.x;
    size_t stride = (size_t)gridDim.x * blockDim.x;
    for (size_t i = tid; i < (size_t)kH * kI; i += stride) w16[i] = (_Float16)wih0[i];
    for (size_t i = tid; i < (size_t)kH * kH; i += stride) {
        wh0_16[i] = (_Float16)whh0[i];
        wi1_16[i] = (_Float16)wih1[i];
        wh1_16[i] = (_Float16)whh1[i];
    }
    for (size_t i = tid; i < kBH; i += stride) {
        out0m[i] = (_Float16)h0[i];          // h(0) layer0 -> slab 0
        h1m[i]   = (_Float16)h0[kBH + i];    // h(0) layer1 -> slab 0
    }
    // sentinel-fill slabs 1..T of both h arrays
    u32x4 s = {0xFFFFFFFFu, 0xFFFFFFFFu, 0xFFFFFFFFu, 0xFFFFFFFFu};
    u32x4* a = (u32x4*)(out0m + kBH);
    u32x4* b = (u32x4*)(h1m + kBH);
    const size_t nf = (size_t)kT * kBH / 8;
    for (size_t i = tid; i < nf; i += stride) { a[i] = s; b[i] = s; }
}

// xw[b][t][c] = sum_i x[b,t,i]*Wih0[c,i] + bih0[c] + bhh0[c]   (fp32, into d_out)
__global__ __launch_bounds__(256) void xw_kernel(
    const float* __restrict__ x, const _Float16* __restrict__ w16,
    const float* __restrict__ bih, const float* __restrict__ bhh, float* xw) {
    const int mb = blockIdx.x >> 3, nb = blockIdx.x & 7;
    const int wave = threadIdx.x >> 6, lane = threadIdx.x & 63;
    const int r = lane & 15, q = lane >> 4;
    const int m0 = mb * 64 + wave * 16;
    half8 a[8];
#pragma unroll
    for (int ko = 0; ko < 8; ++ko)
        a[ko] = cvt8(x + (size_t)(m0 + r) * kI + ko * 32 + q * 8);
#pragma unroll
    for (int ct = 0; ct < 4; ++ct) {
        const int cc = nb * 64 + ct * 16 + r;
        const float bias = bih[cc] + bhh[cc];
        floatx4 acc = {bias, bias, bias, bias};
#pragma unroll
        for (int ko = 0; ko < 8; ++ko) {
            half8 b = *(const half8*)(w16 + (size_t)cc * kI + ko * 32 + q * 8);
            acc = MFMA(a[ko], b, acc);
        }
#pragma unroll
        for (int j = 0; j < 4; ++j)
            xw[(size_t)(m0 + q * 4 + j) * kH + cc] = acc[j];
    }
}

// ---------------------------------------------------------------------------
__global__ __launch_bounds__(1024) void scan_kernel(
    const float* xw,                       // = d_out (fp32 [B][T][H]), layer0 reads
    _Float16* out0m, _Float16* h1m,
    float* out1,                           // = d_out, layer1 writes
    const _Float16* __restrict__ wh0_16,
    const _Float16* __restrict__ wi1_16, const _Float16* __restrict__ wh1_16,
    const float* __restrict__ bih1, const float* __restrict__ bhh1) {
    __shared__ __align__(16) char smem[45056];

    const int blk = blockIdx.x;
    const int tid = threadIdx.x;
    const int wave = tid >> 6, lane = tid & 63;
    const int r = lane & 15, q = lane >> 4;
    const int rb = (r << 10), swz = (r & 7) << 4;    // MFMA A-read addressing
    const int rr = lane >> 2, cg = lane & 3;         // publish-transpose roles

    if (blk < 8) {
        // ===== layer 0: 4 groups x 2 halves, 16 waves x 16 cols, full-K =====
        const int g = blk >> 1, hf = blk & 1;
        const int b0 = g * 16;
        const int cc = hf * 256 + wave * 16 + r;     // weight row / output col
        half8 wfh[16];                               // full-K fp16 weights
#pragma unroll
        for (int ks = 0; ks < 16; ++ks)
            wfh[ks] = *(const half8*)(wh0_16 + (size_t)cc * kH + ks * 32 + q * 8);
        // cooperative staging: one 16B unit / thread covers [16][512] fp16
        const int srow = tid >> 6, sunit = tid & 63;
        const size_t sg_off = (size_t)(b0 + srow) * kH + sunit * 8;
        const int sdoff = ((srow << 10) | (sunit << 4)) ^ ((srow & 7) << 4);
        char* ts = smem + 32768 + wave * 512;        // per-wave [16][16] fp16
        _Float16* st = out0m + (size_t)kBH + (size_t)(b0 + rr) * kH
                       + hf * 256 + wave * 16 + cg * 4;

        for (int t = 0; t < kT; ++t) {
            char* bufS = (t & 1) ? smem + 16384 : smem;   // stage double-buffer
            float xwv[4];                            // epilogue-only, pre-gate
#pragma unroll
            for (int j = 0; j < 4; ++j)
                xwv[j] = xw[((size_t)(b0 + q * 4 + j) * kT + t) * kH + cc];
            // sentinel poll: my 16B unit of h(t); detect == data in register
            u32x4 sv;
            {
                const _Float16* sgp = out0m + (size_t)t * kBH + sg_off;
                int guard = 0;
                for (;;) {
                    LLC_LOAD16(sv, sgp);
                    __builtin_amdgcn_s_waitcnt(0x0F70);       // vmcnt(0)
                    __builtin_amdgcn_sched_barrier(0);
                    if (!__any(dirty4(sv))) break;
                    if (++guard > (1 << 22)) break;           // fail-wrong, not hang
                }
            }
            *(u32x4*)(bufS + sdoff) = sv;
            __syncthreads();                         // S: tile staged (only barrier)
            floatx4 acc = {0.f, 0.f, 0.f, 0.f};
#pragma unroll
            for (int ks = 0; ks < 16; ++ks) {
                half8 la = *(const half8*)(bufS + ((rb | (ks << 6) | (q << 4)) ^ swz));
                acc = MFMA(la, wfh[ks], acc);
            }
            // epilogue: tanh -> per-wave transpose -> coalesced 8B sc1 store
#pragma unroll
            for (int j = 0; j < 4; ++j) {
                float v = fast_tanh(acc[j] + xwv[j]);
                *(_Float16*)(ts + (q * 4 + j) * 32 + r * 2) = (_Float16)v;
            }
            asm volatile("s_waitcnt lgkmcnt(0)" ::: "memory");
            u32x2 tv = *(const u32x2*)(ts + rr * 32 + cg * 8);
            agent_store8(st, tv);                    // data IS the notification
            st += kBH;
        }
    } else {
        // ===== layer 1: 4 groups x 4 quarters, 8 (hh|ih) wave pairs, full-K =====
        const int b2 = blk - 8;
        const int g = b2 >> 2, qb = b2 & 3;
        const int b0 = g * 16;
        const int ct = wave >> 1, part = wave & 1;   // pair ct, part0=hh part1=ih
        const int cc = qb * 128 + ct * 16 + r;
        half8 wf[16];                                // one matrix full-K fp16
        const _Float16* wsrc = part ? wi1_16 : wh1_16;
#pragma unroll
        for (int ks = 0; ks < 16; ++ks)
            wf[ks] = *(const half8*)(wsrc + (size_t)cc * kH + ks * 32 + q * 8);
        const float bias = (part == 0) ? (bih1[cc] + bhh1[cc]) : 0.f;
        // staging: 512 threads per part, two 16B units each -> [16][512] fp16
        const int u = ct * 64 + lane;
        const int srow = u >> 5, sunit = u & 31;
        const size_t sg_off = (size_t)(b0 + srow) * kH + sunit * 16;
        const int tbase = part ? 16384 : 0;
        char* sd0 = smem + tbase + (((srow << 10) | (sunit << 5)) ^ ((srow & 7) << 4));
        char* sd1 = smem + tbase + ((((srow << 10) | (sunit << 5)) | 16) ^ ((srow & 7) << 4));
        float* redp = (float*)(smem + 32768) + (ct * 256 + lane * 4);
        char* tsp = smem + 40960 + ct * 512;         // per-pair [16][16] fp16 (part0)
        _Float16* hst = h1m + (size_t)kBH + (size_t)(b0 + rr) * kH
                        + qb * 128 + ct * 16 + cg * 4;
        float* o1 = out1 + (size_t)(b0 + q * 4) * kT * kH + cc;

        for (int t = 0; t < kT; ++t) {
            // sentinel poll: part0 -> h1(t), part1 -> out0(t+1); 2 x 16B units
            const _Float16* sl = (part == 0) ? h1m + (size_t)t * kBH
                                             : out0m + (size_t)(t + 1) * kBH;
            const _Float16* base = sl + sg_off;
            u32x4 s0, s1;
            {
                int guard = 0;
                for (;;) {
                    LLC_LOAD16(s0, base);
                    LLC_LOAD16(s1, base + 8);
                    __builtin_amdgcn_s_waitcnt(0x0F70);       // vmcnt(0)
                    __builtin_amdgcn_sched_barrier(0);
                    if (!__any(dirty4(s0) | dirty4(s1))) break;
                    if (++guard > (1 << 22)) break;           // fail-wrong, not hang
                }
            }
            *(u32x4*)sd0 = s0;
            *(u32x4*)sd1 = s1;
            __syncthreads();                         // S: both tiles staged
            floatx4 acc = {0.f, 0.f, 0.f, 0.f};
            const char* tb = smem + tbase;
#pragma unroll
            for (int ks = 0; ks < 16; ++ks) {
                half8 la = *(const half8*)(tb + ((rb | (ks << 6) | (q << 4)) ^ swz));
                acc = MFMA(la, wf[ks], acc);
            }
            if (part == 1) *(floatx4*)redp = acc;
            __syncthreads();                         // R: partials ready + reuse fence
            if (part == 0) {
                floatx4 o = *(const floatx4*)redp;
                float vj[4];
#pragma unroll
                for (int j = 0; j < 4; ++j) {
                    vj[j] = fast_tanh(acc[j] + o[j] + bias);
                    *(_Float16*)(tsp + (q * 4 + j) * 32 + r * 2) = (_Float16)vj[j];
                }
                asm volatile("s_waitcnt lgkmcnt(0)" ::: "memory");
                u32x2 tv = *(const u32x2*)(tsp + rr * 32 + cg * 8);
                agent_store8(hst, tv);               // data IS the notification
#pragma unroll
                for (int j = 0; j < 4; ++j)
                    o1[(size_t)j * kT * kH + (size_t)t * kH] = vj[j];
            }
            hst += kBH;
        }
    }
}

__global__ void finalize_kernel(const _Float16* __restrict__ out0m,
                                const _Float16* __restrict__ h1m,
                                float* __restrict__ out) {
    int idx = blockIdx.x * blockDim.x + threadIdx.x;  // 0 .. 65535
    float* hn = out + (size_t)kB * kT * kH;
    if (idx < kBH) hn[idx] = (float)out0m[(size_t)kT * kBH + idx];
    else hn[idx] = (float)h1m[(size_t)kT * kBH + (idx - kBH)];
}

extern "C" void kernel_launch(void* const* d_in, const int* in_sizes, int n_in,
                              void* d_out, int out_size, void* d_ws, size_t ws_size,
                              hipStream_t stream) {
    const float* x    = (const float*)d_in[0];
    const float* h0in = (const float*)d_in[1];
    const float* wih0 = (const float*)d_in[2];
    const float* whh0 = (const float*)d_in[3];
    const float* bih0 = (const float*)d_in[4];
    const float* bhh0 = (const float*)d_in[5];
    const float* wih1 = (const float*)d_in[6];
    const float* whh1 = (const float*)d_in[7];
    const float* bih1 = (const float*)d_in[8];
    const float* bhh1 = (const float*)d_in[9];
    float* out = (float*)d_out;
    char* ws = (char*)d_ws;

    _Float16* w16    = (_Float16*)(ws + W16_B);
    _Float16* wh0_16 = (_Float16*)(ws + WH0_B);
    _Float16* wi1_16 = (_Float16*)(ws + WI1_B);
    _Float16* wh1_16 = (_Float16*)(ws + WH1_B);
    _Float16* out0m  = (_Float16*)(ws + OUT0M_B);
    _Float16* h1m    = (_Float16*)(ws + H1M_B);

    setup_kernel<<<2048, 256, 0, stream>>>(h0in, wih0, whh0, wih1, whh1,
                                           w16, wh0_16, wi1_16, wh1_16, out0m, h1m);
    xw_kernel<<<4096, 256, 0, stream>>>(x, w16, bih0, bhh0, out);
    scan_kernel<<<24, 1024, 0, stream>>>(out, out0m, h1m, out,
                                         wh0_16, wi1_16, wh1_16, bih1, bhh1);
    finalize_kernel<<<256, 256, 0, stream>>>(out0m, h1m, out);
}